// Round 19
// baseline (149.426 us; speedup 1.0000x reference)
//
#include <hip/hip_runtime.h>
#include <hip/hip_bf16.h>

// GraphSAGE 2-layer, N=100000, E=1200000, D: 64 -> 64 -> 32, fp32 in/out.
// R19: 4-node pipelined gathers. R18 gathers were dependency-chain latency
// bound (info->nbr->feat, ~2300 cyc serial, one node per wave, ~38us each).
// Now each wave owns 4 consecutive nodes: one info load + readlane bcast,
// then 4 independent nb/feat chains in flight per loop iteration (4x MLP).
// Masks are wave-uniform (m8/m16 multiples of batch); invalid slots read
// the sentinel zero row -> arithmetic identical to R18 (absmax 0.03125).
// Rest = R18: MFMA dense (y2l/y2r push-through), atomic-free 256-queue
// build, pad-16 LDS CSR, bf16 activations, fused gather_out epilogue.

#define D1 64
#define NQ 256
#define SUBN 391
#define QCAP 5632
#define LCAP 11520
#define BE 5120

typedef __attribute__((ext_vector_type(8))) short bf16x8;
typedef __attribute__((ext_vector_type(4))) float f32x4;

static __device__ __forceinline__ float bf2f(ushort u) {
    unsigned int x = ((unsigned int)u) << 16;
    return __uint_as_float(x);
}
static __device__ __forceinline__ ushort f2bf(float f) {
    union { __hip_bfloat16 b; ushort u; } cv;
    cv.b = __float2bfloat16(f);   // RNE
    return cv.u;
}
static __device__ __forceinline__ float lo2f(unsigned u) {
    return __uint_as_float(u << 16);
}
static __device__ __forceinline__ float hi2f(unsigned u) {
    return __uint_as_float(u & 0xffff0000u);
}
static __device__ __forceinline__ unsigned packbf(float x, float y) {
    return (unsigned)f2bf(x) | ((unsigned)f2bf(y) << 16);
}

// ---- phase A: compact edges into 256 sub-partition queues ----------------

__global__ __launch_bounds__(256)
void compact_edges256(const int* __restrict__ src, const int* __restrict__ dst,
                      int* __restrict__ tail, int2* __restrict__ queue, int E) {
    __shared__ int hist[NQ];
    __shared__ int base[NQ];
    int tid = threadIdx.x;
    int e0 = blockIdx.x * BE;
    int e1 = min(E, e0 + BE);

    hist[tid] = 0;
    __syncthreads();
    for (int e = e0 + tid; e < e1; e += 256)
        atomicAdd(&hist[dst[e] / SUBN], 1);          // LDS atomic
    __syncthreads();
    base[tid] = atomicAdd(&tail[tid], hist[tid]);    // 256 global atomics/blk
    hist[tid] = 0;                                   // reuse as cursor
    __syncthreads();
    for (int e = e0 + tid; e < e1; e += 256) {
        int d = dst[e];
        int s = src[e];
        int p = d / SUBN;
        int pos = base[p] + atomicAdd(&hist[p], 1);  // LDS atomic
        if (pos < QCAP) queue[(size_t)p * QCAP + pos] = make_int2(s, d);
    }
}

// ---- phase B: per-sub-partition exact CSR built entirely in LDS ---------

__global__ __launch_bounds__(256)
void csr_build_local(const int2* __restrict__ queue, const int* __restrict__ tail,
                     int2* __restrict__ info, int* __restrict__ nbr, int N) {
    __shared__ int lcnt[512];
    __shared__ int psum[256];
    __shared__ int lnbr[LCAP];
    int tid = threadIdx.x;
    int p = blockIdx.x;
    int lo = p * SUBN;
    int nt = min(tail[p], QCAP);
    const int2* q = queue + (size_t)p * QCAP;
    int gbase = p * LCAP;

    lcnt[tid] = 0; lcnt[tid + 256] = 0;
    __syncthreads();
    for (int e = tid; e < nt; e += 256)
        atomicAdd(&lcnt[q[e].y - lo], 1);
    __syncthreads();

    int d0 = lcnt[2 * tid], d1 = lcnt[2 * tid + 1];
    int p0 = (d0 + 15) & ~15, p1 = (d1 + 15) & ~15;
    int s = p0 + p1;
    psum[tid] = s;
    __syncthreads();
    for (int off = 1; off < 256; off <<= 1) {
        int a = (tid >= off) ? psum[tid - off] : 0;
        __syncthreads();
        psum[tid] += a;
        __syncthreads();
    }
    int st0 = psum[tid] - s;
    int st1 = st0 + p0;
    int ptot = psum[255];

    {
        int li = 2 * tid, n = lo + li;
        if (li < SUBN && n < N) info[n] = make_int2(gbase + st0, d0);
        lcnt[li] = st0;
        li = 2 * tid + 1; n = lo + li;
        if (li < SUBN && n < N) info[n] = make_int2(gbase + st1, d1);
        lcnt[li] = st1;
    }
    __syncthreads();

    for (int e = tid; e < nt; e += 256) {
        int2 pr = q[e];
        int pos = atomicAdd(&lcnt[pr.y - lo], 1);
        lnbr[pos] = pr.x;
    }
    __syncthreads();

    for (int j = st0 + d0; j < st0 + p0; ++j) lnbr[j] = N;
    for (int j = st1 + d1; j < st1 + p1; ++j) lnbr[j] = N;
    __syncthreads();

    for (int i = tid; i < ptot; i += 256)
        nbr[gbase + i] = lnbr[i];
}

// ---- fp32->bf16 convert + init + weight transpose to [j][k] bf16 --------

__global__ __launch_bounds__(256)
void cvt_bf16_init(const float* __restrict__ in, ushort* __restrict__ xh,
                   ushort* __restrict__ y2l, int* __restrict__ tail,
                   const float* __restrict__ W1l, const float* __restrict__ W1r,
                   const float* __restrict__ W2l, const float* __restrict__ W2r,
                   ushort* __restrict__ WB1, ushort* __restrict__ WB2,
                   int n4, int N) {
    int i = blockIdx.x * 256 + threadIdx.x;
    if (i < n4) {
        float4 v = *(const float4*)&in[(size_t)i * 4];
        ushort4 u;
        u.x = f2bf(v.x); u.y = f2bf(v.y); u.z = f2bf(v.z); u.w = f2bf(v.w);
        *(ushort4*)&xh[(size_t)i * 4] = u;
    }
    if (blockIdx.x == 0) tail[threadIdx.x] = 0;
    if (blockIdx.x == 1) {                          // zero sentinel rows
        if (threadIdx.x < D1) xh[(size_t)N * D1 + threadIdx.x] = 0;
        if (threadIdx.x < 32) y2l[(size_t)N * 32 + threadIdx.x] = 0;
    }
    if (blockIdx.x == 2) {                          // WB1[j][k], k<64: W1l
        for (int idx = threadIdx.x; idx < 64 * 128; idx += 256) {
            int j = idx >> 7, k = idx & 127;
            float v = (k < 64) ? W1l[k * 64 + j] : W1r[(k - 64) * 64 + j];
            WB1[idx] = f2bf(v);
        }
    }
    if (blockIdx.x == 3) {                          // WB2[j2][k]
        for (int idx = threadIdx.x; idx < 64 * 64; idx += 256) {
            int j2 = idx >> 6, k = idx & 63;
            float v = (j2 < 32) ? W2l[k * 32 + j2] : W2r[k * 32 + (j2 - 32)];
            WB2[idx] = f2bf(v);
        }
    }
}

// ---- gather L1: 4 nodes per wave, 8-row batches of 128B rows ------------

#define ACC8J(j, u) do { \
    acc[j][0] += lo2f((u).x); acc[j][1] += hi2f((u).x); \
    acc[j][2] += lo2f((u).y); acc[j][3] += hi2f((u).y); \
    acc[j][4] += lo2f((u).z); acc[j][5] += hi2f((u).z); \
    acc[j][6] += lo2f((u).w); acc[j][7] += hi2f((u).w); } while (0)

__global__ __launch_bounds__(256)
void gather_mean8_x4(const ushort* __restrict__ feat,
                     const int2* __restrict__ info,
                     const int* __restrict__ nbr,
                     ushort* __restrict__ mean, int N) {
    int w    = threadIdx.x >> 6;
    int lane = threadIdx.x & 63;
    int base = (blockIdx.x * 4 + w) * 4;     // first of this wave's 4 nodes
    if (base >= N) return;
    int r = lane >> 3;          // neighbor slot 0..7
    int c = lane & 7;           // uint4 quad within 64-feature row
    const uint4* f4 = (const uint4*)feat;

    int2 ii = info[min(base + (lane & 3), N - 1)];
    int st[4], dg[4], m8[4];
    #pragma unroll
    for (int j = 0; j < 4; ++j) {
        st[j] = __shfl(ii.x, j, 64);
        dg[j] = __shfl(ii.y, j, 64);
        m8[j] = (base + j < N) ? ((dg[j] + 7) & ~7) : 0;
    }
    int mmax = max(max(m8[0], m8[1]), max(m8[2], m8[3]));

    float acc[4][8];
    #pragma unroll
    for (int j = 0; j < 4; ++j)
        #pragma unroll
        for (int k = 0; k < 8; ++k) acc[j][k] = 0.0f;

    for (int i = 0; i < mmax; i += 8) {
        int e[4];
        #pragma unroll
        for (int j = 0; j < 4; ++j) {
            bool v = i < m8[j];                     // wave-uniform
            int ee = nbr[st[j] + (v ? i + r : 0)];  // addr always in-bounds
            e[j] = v ? ee : N;                      // sentinel zero row
        }
        #pragma unroll
        for (int j = 0; j < 4; ++j) {
            uint4 u = f4[(size_t)e[j] * 8 + c];
            ACC8J(j, u);
        }
    }

    #pragma unroll
    for (int j = 0; j < 4; ++j)
        #pragma unroll
        for (int k = 0; k < 8; ++k) {
            acc[j][k] += __shfl_xor(acc[j][k], 8, 64);
            acc[j][k] += __shfl_xor(acc[j][k], 16, 64);
            acc[j][k] += __shfl_xor(acc[j][k], 32, 64);
        }

    #pragma unroll
    for (int j = 0; j < 4; ++j) {
        if (r == 0 && base + j < N) {       // lanes 0..7 write 128B row
            float inv = 1.0f / fmaxf((float)dg[j], 1.0f);
            uint4 o;
            o.x = packbf(acc[j][0] * inv, acc[j][1] * inv);
            o.y = packbf(acc[j][2] * inv, acc[j][3] * inv);
            o.z = packbf(acc[j][4] * inv, acc[j][5] * inv);
            o.w = packbf(acc[j][6] * inv, acc[j][7] * inv);
            ((uint4*)mean)[(size_t)(base + j) * 8 + c] = o;
        }
    }
}

// ---- gather L2 + output: 4 nodes/wave, 16-row batches of 64B y2l rows ----
// out[n] = mean(y2l[nbrs]) + y2r[n] + b2

__global__ __launch_bounds__(256)
void gather_out_x4(const ushort* __restrict__ y2l,
                   const float* __restrict__ y2r,
                   const float* __restrict__ b2,
                   const int2* __restrict__ info,
                   const int* __restrict__ nbr,
                   float* __restrict__ outp, int N) {
    int w    = threadIdx.x >> 6;
    int lane = threadIdx.x & 63;
    int base = (blockIdx.x * 4 + w) * 4;
    if (base >= N) return;
    int r = lane >> 2;          // neighbor slot 0..15
    int c = lane & 3;           // uint4 quad within 32-feature row
    const uint4* f4 = (const uint4*)y2l;

    int2 ii = info[min(base + (lane & 3), N - 1)];
    int st[4], dg[4], m16[4];
    #pragma unroll
    for (int j = 0; j < 4; ++j) {
        st[j]  = __shfl(ii.x, j, 64);
        dg[j]  = __shfl(ii.y, j, 64);
        m16[j] = (base + j < N) ? ((dg[j] + 15) & ~15) : 0;
    }
    int mmax = max(max(m16[0], m16[1]), max(m16[2], m16[3]));

    float acc[4][8];
    #pragma unroll
    for (int j = 0; j < 4; ++j)
        #pragma unroll
        for (int k = 0; k < 8; ++k) acc[j][k] = 0.0f;

    for (int i = 0; i < mmax; i += 16) {
        int e[4];
        #pragma unroll
        for (int j = 0; j < 4; ++j) {
            bool v = i < m16[j];                    // wave-uniform
            int ee = nbr[st[j] + (v ? i + r : 0)];
            e[j] = v ? ee : N;
        }
        #pragma unroll
        for (int j = 0; j < 4; ++j) {
            uint4 u = f4[(size_t)e[j] * 4 + c];
            ACC8J(j, u);
        }
    }

    #pragma unroll
    for (int j = 0; j < 4; ++j)
        #pragma unroll
        for (int k = 0; k < 8; ++k) {
            acc[j][k] += __shfl_xor(acc[j][k], 4, 64);
            acc[j][k] += __shfl_xor(acc[j][k], 8, 64);
            acc[j][k] += __shfl_xor(acc[j][k], 16, 64);
            acc[j][k] += __shfl_xor(acc[j][k], 32, 64);
        }

    #pragma unroll
    for (int j = 0; j < 4; ++j) {
        if (r == 0 && base + j < N) {       // lanes 0..3: 32B fp32 chunks
            float inv = 1.0f / fmaxf((float)dg[j], 1.0f);
            size_t o = (size_t)(base + j) * 32 + c * 8;
            float4 r0 = *(const float4*)&y2r[o];
            float4 r1 = *(const float4*)&y2r[o + 4];
            float4 v0, v1;
            v0.x = fmaf(acc[j][0], inv, r0.x + b2[c * 8 + 0]);
            v0.y = fmaf(acc[j][1], inv, r0.y + b2[c * 8 + 1]);
            v0.z = fmaf(acc[j][2], inv, r0.z + b2[c * 8 + 2]);
            v0.w = fmaf(acc[j][3], inv, r0.w + b2[c * 8 + 3]);
            v1.x = fmaf(acc[j][4], inv, r1.x + b2[c * 8 + 4]);
            v1.y = fmaf(acc[j][5], inv, r1.y + b2[c * 8 + 5]);
            v1.z = fmaf(acc[j][6], inv, r1.z + b2[c * 8 + 6]);
            v1.w = fmaf(acc[j][7], inv, r1.w + b2[c * 8 + 7]);
            *(float4*)&outp[o] = v0;
            *(float4*)&outp[o + 4] = v1;
        }
    }
}

// ---- dense (MFMA): h = relu([mean|x]@W1 + b1); y2l=h@W2l; y2r=h@W2r -----

__global__ __launch_bounds__(256)
void dense_mfma(const ushort* __restrict__ Am,     // mean1 [N][64] bf16
                const ushort* __restrict__ Ax,     // xh [N+1][64] bf16
                const ushort* __restrict__ WB1,    // [64 j][128 k] bf16
                const ushort* __restrict__ WB2,    // [64 j2][64 k] bf16
                const float* __restrict__ b1,      // [64]
                ushort* __restrict__ y2l,          // [N+1][32] bf16
                float* __restrict__ y2r,           // [N][32] fp32
                int N) {
    __shared__ ushort hl[4][16 * 72];   // per-wave h tile, stride 72
    int tid  = threadIdx.x;
    int w    = tid >> 6;
    int lane = tid & 63;
    int mrow = lane & 15;
    int kg   = lane >> 4;
    int nbase = blockIdx.x * 64 + w * 16;
    int arow = min(nbase + mrow, N - 1);

    bf16x8 a[4];
    a[0] = *(const bf16x8*)&Am[(size_t)arow * 64 +      kg * 8];
    a[1] = *(const bf16x8*)&Am[(size_t)arow * 64 + 32 + kg * 8];
    a[2] = *(const bf16x8*)&Ax[(size_t)arow * 64 +      kg * 8];
    a[3] = *(const bf16x8*)&Ax[(size_t)arow * 64 + 32 + kg * 8];

    f32x4 acc[4];
    #pragma unroll
    for (int t = 0; t < 4; ++t) acc[t] = (f32x4){0.f, 0.f, 0.f, 0.f};

    #pragma unroll
    for (int s = 0; s < 4; ++s) {
        #pragma unroll
        for (int t = 0; t < 4; ++t) {
            bf16x8 b = *(const bf16x8*)&WB1[(size_t)(t * 16 + mrow) * 128 + s * 32 + kg * 8];
            acc[t] = __builtin_amdgcn_mfma_f32_16x16x32_bf16(a[s], b, acc[t], 0, 0, 0);
        }
    }

    #pragma unroll
    for (int t = 0; t < 4; ++t) {
        float bv = b1[t * 16 + mrow];
        #pragma unroll
        for (int r = 0; r < 4; ++r) {
            float hv = fmaxf(acc[t][r] + bv, 0.0f);
            hl[w][(kg * 4 + r) * 72 + t * 16 + mrow] = f2bf(hv);
        }
    }
    // same-wave write->read: DS ops in order, no barrier needed

    bf16x8 a2[2];
    a2[0] = *(const bf16x8*)&hl[w][mrow * 72 +      kg * 8];
    a2[1] = *(const bf16x8*)&hl[w][mrow * 72 + 32 + kg * 8];

    f32x4 acc2[4];
    #pragma unroll
    for (int t = 0; t < 4; ++t) acc2[t] = (f32x4){0.f, 0.f, 0.f, 0.f};

    #pragma unroll
    for (int s = 0; s < 2; ++s) {
        #pragma unroll
        for (int t = 0; t < 4; ++t) {
            bf16x8 b = *(const bf16x8*)&WB2[(size_t)(t * 16 + mrow) * 64 + s * 32 + kg * 8];
            acc2[t] = __builtin_amdgcn_mfma_f32_16x16x32_bf16(a2[s], b, acc2[t], 0, 0, 0);
        }
    }

    #pragma unroll
    for (int t = 0; t < 2; ++t) {
        #pragma unroll
        for (int r = 0; r < 4; ++r) {
            int grow = nbase + kg * 4 + r;
            if (grow < N)
                y2l[(size_t)grow * 32 + t * 16 + mrow] = f2bf(acc2[t][r]);
        }
    }
    #pragma unroll
    for (int t = 2; t < 4; ++t) {
        #pragma unroll
        for (int r = 0; r < 4; ++r) {
            int grow = nbase + kg * 4 + r;
            if (grow < N)
                y2r[(size_t)grow * 32 + (t - 2) * 16 + mrow] = acc2[t][r];
        }
    }
}

// ---- launch -------------------------------------------------------------

extern "C" void kernel_launch(void* const* d_in, const int* in_sizes, int n_in,
                              void* d_out, int out_size, void* d_ws, size_t ws_size,
                              hipStream_t stream) {
    const float* x   = (const float*)d_in[0];
    const int*   ei  = (const int*)d_in[1];
    const float* W1l = (const float*)d_in[2];
    const float* W1r = (const float*)d_in[3];
    const float* b1  = (const float*)d_in[4];
    const float* W2l = (const float*)d_in[5];
    const float* W2r = (const float*)d_in[6];
    const float* b2  = (const float*)d_in[7];
    float* out = (float*)d_out;

    int N = in_sizes[0] / D1;
    int E = in_sizes[1] / 2;
    const int* src = ei;
    const int* dst = ei + E;

    char* ws = (char*)d_ws;
    auto alignup = [](size_t v) { return (v + 255) & ~(size_t)255; };
    size_t off = 0;
    int*    tail  = (int*)(ws + off);    off += alignup(NQ * 4);
    int2*   queue = (int2*)(ws + off);   off += alignup((size_t)NQ * QCAP * 8);
    int*    nbr   = (int*)(ws + off);    off += alignup((size_t)NQ * LCAP * 4);
    int2*   info  = (int2*)(ws + off);   off += alignup((size_t)N * 8);
    ushort* xh    = (ushort*)(ws + off); off += alignup((size_t)(N + 1) * D1 * 2);
    ushort* y2l   = (ushort*)(ws + off); off += alignup((size_t)(N + 1) * 32 * 2);
    float*  y2r   = (float*)(ws + off);  off += alignup((size_t)N * 32 * 4);
    ushort* WB1   = (ushort*)(ws + off); off += alignup(64 * 128 * 2);
    ushort* WB2   = (ushort*)(ws + off); off += alignup(64 * 64 * 2);
    // layer-1 mean lives in d_out: written by gather1, read by dense_mfma,
    // then d_out is fully overwritten by gather_out with the final output.
    ushort* mean1 = (ushort*)d_out;      // N*64*2B = 12.8MB == out_size bytes

    int g4 = (N + 15) / 16;       // gathers: 4 nodes/wave, 4 waves/block
    int db = (N + 63) / 64;
    int cb = ((N * D1 / 4) + 255) / 256;
    int ab = (E + BE - 1) / BE;

    cvt_bf16_init<<<cb, 256, 0, stream>>>(x, xh, y2l, tail,
                                          W1l, W1r, W2l, W2r, WB1, WB2,
                                          N * D1 / 4, N);
    compact_edges256<<<ab, 256, 0, stream>>>(src, dst, tail, queue, E);
    csr_build_local<<<NQ, 256, 0, stream>>>(queue, tail, info, nbr, N);

    gather_mean8_x4<<<g4, 256, 0, stream>>>(xh, info, nbr, mean1, N);
    dense_mfma<<<db, 256, 0, stream>>>(mean1, xh, WB1, WB2, b1, y2l, y2r, N);
    gather_out_x4<<<g4, 256, 0, stream>>>(y2l, y2r, b2, info, nbr, out, N);
}

// Round 20
// 141.716 us; speedup vs baseline: 1.0544x; 1.0544x over previous
//
#include <hip/hip_runtime.h>
#include <hip/hip_bf16.h>

// GraphSAGE 2-layer, N=100000, E=1200000, D: 64 -> 64 -> 32, fp32 in/out.
// R20: revert R19's 4-node gathers (regressed: -4us, occ 66->39, VALU up,
// mmax imbalance; gathers are issue-structure bound at ~40us/~35us floors
// for 1-node waves) back to R18 form, and merge cvt_bf16_init INTO the
// compact kernel (block-role split): cvt's 6us of BW-streaming overlaps
// compact's LDS-atomic work, one dispatch boundary removed. tail zeroing
// via 1KB hipMemsetAsync before the merged kernel.
// Pipeline: memset(tail) -> build_and_cvt -> csr_build -> gather_mean8 ->
// dense_mfma -> gather_out. MFMA dense w/ layer-2 push-through (R18),
// atomic-free 256-queue build + pad-16 LDS CSR (R14), bf16 activations.

#define D1 64
#define NQ 256
#define SUBN 391
#define QCAP 5632
#define LCAP 11520
#define BE 5120

typedef __attribute__((ext_vector_type(8))) short bf16x8;
typedef __attribute__((ext_vector_type(4))) float f32x4;

static __device__ __forceinline__ float bf2f(ushort u) {
    unsigned int x = ((unsigned int)u) << 16;
    return __uint_as_float(x);
}
static __device__ __forceinline__ ushort f2bf(float f) {
    union { __hip_bfloat16 b; ushort u; } cv;
    cv.b = __float2bfloat16(f);   // RNE
    return cv.u;
}
static __device__ __forceinline__ float lo2f(unsigned u) {
    return __uint_as_float(u << 16);
}
static __device__ __forceinline__ float hi2f(unsigned u) {
    return __uint_as_float(u & 0xffff0000u);
}
static __device__ __forceinline__ unsigned packbf(float x, float y) {
    return (unsigned)f2bf(x) | ((unsigned)f2bf(y) << 16);
}

// ---- merged: edge compaction (blocks < ab) + cvt/init (blocks >= ab) ----

__global__ __launch_bounds__(256)
void build_and_cvt(const int* __restrict__ src, const int* __restrict__ dst,
                   int* __restrict__ tail, int2* __restrict__ queue, int E,
                   const float* __restrict__ in, ushort* __restrict__ xh,
                   ushort* __restrict__ y2l,
                   const float* __restrict__ W1l, const float* __restrict__ W1r,
                   const float* __restrict__ W2l, const float* __restrict__ W2r,
                   ushort* __restrict__ WB1, ushort* __restrict__ WB2,
                   int n4, int N, int ab) {
    int tid = threadIdx.x;
    if ((int)blockIdx.x < ab) {
        // ---- compact role: two streaming passes over this block's edges
        __shared__ int hist[NQ];
        __shared__ int base[NQ];
        int e0 = blockIdx.x * BE;
        int e1 = min(E, e0 + BE);

        hist[tid] = 0;
        __syncthreads();
        for (int e = e0 + tid; e < e1; e += 256)
            atomicAdd(&hist[dst[e] / SUBN], 1);          // LDS atomic
        __syncthreads();
        base[tid] = atomicAdd(&tail[tid], hist[tid]);    // 256 global/blk
        hist[tid] = 0;                                   // reuse as cursor
        __syncthreads();
        for (int e = e0 + tid; e < e1; e += 256) {
            int d = dst[e];
            int s = src[e];
            int p = d / SUBN;
            int pos = base[p] + atomicAdd(&hist[p], 1);  // LDS atomic
            if (pos < QCAP) queue[(size_t)p * QCAP + pos] = make_int2(s, d);
        }
    } else {
        // ---- cvt role
        int b = blockIdx.x - ab;
        int i = b * 256 + tid;
        if (i < n4) {
            float4 v = *(const float4*)&in[(size_t)i * 4];
            ushort4 u;
            u.x = f2bf(v.x); u.y = f2bf(v.y); u.z = f2bf(v.z); u.w = f2bf(v.w);
            *(ushort4*)&xh[(size_t)i * 4] = u;
        }
        if (b == 0) {                               // zero sentinel rows
            if (tid < D1) xh[(size_t)N * D1 + tid] = 0;
            if (tid < 32) y2l[(size_t)N * 32 + tid] = 0;
        }
        if (b == 1) {                               // WB1[j][k]
            for (int idx = tid; idx < 64 * 128; idx += 256) {
                int j = idx >> 7, k = idx & 127;
                float v = (k < 64) ? W1l[k * 64 + j] : W1r[(k - 64) * 64 + j];
                WB1[idx] = f2bf(v);
            }
        }
        if (b == 2) {                               // WB2[j2][k]
            for (int idx = tid; idx < 64 * 64; idx += 256) {
                int j2 = idx >> 6, k = idx & 63;
                float v = (j2 < 32) ? W2l[k * 32 + j2] : W2r[k * 32 + (j2 - 32)];
                WB2[idx] = f2bf(v);
            }
        }
    }
}

// ---- phase B: per-sub-partition exact CSR built entirely in LDS ---------

__global__ __launch_bounds__(256)
void csr_build_local(const int2* __restrict__ queue, const int* __restrict__ tail,
                     int2* __restrict__ info, int* __restrict__ nbr, int N) {
    __shared__ int lcnt[512];
    __shared__ int psum[256];
    __shared__ int lnbr[LCAP];
    int tid = threadIdx.x;
    int p = blockIdx.x;
    int lo = p * SUBN;
    int nt = min(tail[p], QCAP);
    const int2* q = queue + (size_t)p * QCAP;
    int gbase = p * LCAP;

    lcnt[tid] = 0; lcnt[tid + 256] = 0;
    __syncthreads();
    for (int e = tid; e < nt; e += 256)
        atomicAdd(&lcnt[q[e].y - lo], 1);
    __syncthreads();

    int d0 = lcnt[2 * tid], d1 = lcnt[2 * tid + 1];
    int p0 = (d0 + 15) & ~15, p1 = (d1 + 15) & ~15;
    int s = p0 + p1;
    psum[tid] = s;
    __syncthreads();
    for (int off = 1; off < 256; off <<= 1) {
        int a = (tid >= off) ? psum[tid - off] : 0;
        __syncthreads();
        psum[tid] += a;
        __syncthreads();
    }
    int st0 = psum[tid] - s;
    int st1 = st0 + p0;
    int ptot = psum[255];

    {
        int li = 2 * tid, n = lo + li;
        if (li < SUBN && n < N) info[n] = make_int2(gbase + st0, d0);
        lcnt[li] = st0;
        li = 2 * tid + 1; n = lo + li;
        if (li < SUBN && n < N) info[n] = make_int2(gbase + st1, d1);
        lcnt[li] = st1;
    }
    __syncthreads();

    for (int e = tid; e < nt; e += 256) {
        int2 pr = q[e];
        int pos = atomicAdd(&lcnt[pr.y - lo], 1);
        lnbr[pos] = pr.x;
    }
    __syncthreads();

    for (int j = st0 + d0; j < st0 + p0; ++j) lnbr[j] = N;
    for (int j = st1 + d1; j < st1 + p1; ++j) lnbr[j] = N;
    __syncthreads();

    for (int i = tid; i < ptot; i += 256)
        nbr[gbase + i] = lnbr[i];
}

// ---- gather L1: mean of 64-wide bf16 rows. Wave per node (R18 form). ----

#define ACC8(u) do { \
    a0 += lo2f((u).x); a1 += hi2f((u).x); \
    a2 += lo2f((u).y); a3 += hi2f((u).y); \
    a4 += lo2f((u).z); a5 += hi2f((u).z); \
    a6 += lo2f((u).w); a7 += hi2f((u).w); } while (0)

__global__ __launch_bounds__(256)
void gather_mean8(const ushort* __restrict__ feat,
                  const int2* __restrict__ info,
                  const int* __restrict__ nbr,
                  ushort* __restrict__ mean, int N) {
    int wid  = (blockIdx.x * 256 + threadIdx.x) >> 6;
    int lane = threadIdx.x & 63;
    if (wid >= N) return;
    int2 ii = info[wid];
    int deg = ii.y;
    int m8 = (deg + 7) & ~7;
    const int* nb = nbr + ii.x;
    int r = lane >> 3;
    int c = lane & 7;
    const uint4* f4 = (const uint4*)feat;

    float a0 = 0, a1 = 0, a2 = 0, a3 = 0, a4 = 0, a5 = 0, a6 = 0, a7 = 0;
    int i = 0;
    for (; i + 16 <= m8; i += 16) {
        int e0 = nb[i + r];
        int e1 = nb[i + 8 + r];
        uint4 u0 = f4[(size_t)e0 * 8 + c];
        uint4 u1 = f4[(size_t)e1 * 8 + c];
        ACC8(u0);
        ACC8(u1);
    }
    if (i < m8) {
        int e0 = nb[i + r];
        uint4 u0 = f4[(size_t)e0 * 8 + c];
        ACC8(u0);
    }

    a0 += __shfl_xor(a0, 8, 64); a0 += __shfl_xor(a0, 16, 64); a0 += __shfl_xor(a0, 32, 64);
    a1 += __shfl_xor(a1, 8, 64); a1 += __shfl_xor(a1, 16, 64); a1 += __shfl_xor(a1, 32, 64);
    a2 += __shfl_xor(a2, 8, 64); a2 += __shfl_xor(a2, 16, 64); a2 += __shfl_xor(a2, 32, 64);
    a3 += __shfl_xor(a3, 8, 64); a3 += __shfl_xor(a3, 16, 64); a3 += __shfl_xor(a3, 32, 64);
    a4 += __shfl_xor(a4, 8, 64); a4 += __shfl_xor(a4, 16, 64); a4 += __shfl_xor(a4, 32, 64);
    a5 += __shfl_xor(a5, 8, 64); a5 += __shfl_xor(a5, 16, 64); a5 += __shfl_xor(a5, 32, 64);
    a6 += __shfl_xor(a6, 8, 64); a6 += __shfl_xor(a6, 16, 64); a6 += __shfl_xor(a6, 32, 64);
    a7 += __shfl_xor(a7, 8, 64); a7 += __shfl_xor(a7, 16, 64); a7 += __shfl_xor(a7, 32, 64);

    if (r == 0) {
        float inv = 1.0f / fmaxf((float)deg, 1.0f);
        uint4 o;
        o.x = packbf(a0 * inv, a1 * inv);
        o.y = packbf(a2 * inv, a3 * inv);
        o.z = packbf(a4 * inv, a5 * inv);
        o.w = packbf(a6 * inv, a7 * inv);
        ((uint4*)mean)[(size_t)wid * 8 + c] = o;
    }
}

// ---- gather L2 + output: out[n] = mean(y2l[nbrs]) + y2r[n] + b2 (R18) ---

__global__ __launch_bounds__(256)
void gather_out(const ushort* __restrict__ y2l,
                const float* __restrict__ y2r,
                const float* __restrict__ b2,
                const int2* __restrict__ info,
                const int* __restrict__ nbr,
                float* __restrict__ outp, int N) {
    int wid  = (blockIdx.x * 256 + threadIdx.x) >> 6;
    int lane = threadIdx.x & 63;
    if (wid >= N) return;
    int2 ii = info[wid];
    int deg = ii.y;
    int m16 = (deg + 15) & ~15;
    const int* nb = nbr + ii.x;
    int r = lane >> 2;
    int c = lane & 3;
    const uint4* f4 = (const uint4*)y2l;

    float a0 = 0, a1 = 0, a2 = 0, a3 = 0, a4 = 0, a5 = 0, a6 = 0, a7 = 0;
    int i = 0;
    for (; i + 32 <= m16; i += 32) {
        int e0 = nb[i + r];
        int e1 = nb[i + 16 + r];
        uint4 u0 = f4[(size_t)e0 * 4 + c];
        uint4 u1 = f4[(size_t)e1 * 4 + c];
        ACC8(u0);
        ACC8(u1);
    }
    if (i < m16) {
        int e0 = nb[i + r];
        uint4 u0 = f4[(size_t)e0 * 4 + c];
        ACC8(u0);
    }

    a0 += __shfl_xor(a0, 4, 64); a0 += __shfl_xor(a0, 8, 64); a0 += __shfl_xor(a0, 16, 64); a0 += __shfl_xor(a0, 32, 64);
    a1 += __shfl_xor(a1, 4, 64); a1 += __shfl_xor(a1, 8, 64); a1 += __shfl_xor(a1, 16, 64); a1 += __shfl_xor(a1, 32, 64);
    a2 += __shfl_xor(a2, 4, 64); a2 += __shfl_xor(a2, 8, 64); a2 += __shfl_xor(a2, 16, 64); a2 += __shfl_xor(a2, 32, 64);
    a3 += __shfl_xor(a3, 4, 64); a3 += __shfl_xor(a3, 8, 64); a3 += __shfl_xor(a3, 16, 64); a3 += __shfl_xor(a3, 32, 64);
    a4 += __shfl_xor(a4, 4, 64); a4 += __shfl_xor(a4, 8, 64); a4 += __shfl_xor(a4, 16, 64); a4 += __shfl_xor(a4, 32, 64);
    a5 += __shfl_xor(a5, 4, 64); a5 += __shfl_xor(a5, 8, 64); a5 += __shfl_xor(a5, 16, 64); a5 += __shfl_xor(a5, 32, 64);
    a6 += __shfl_xor(a6, 4, 64); a6 += __shfl_xor(a6, 8, 64); a6 += __shfl_xor(a6, 16, 64); a6 += __shfl_xor(a6, 32, 64);
    a7 += __shfl_xor(a7, 4, 64); a7 += __shfl_xor(a7, 8, 64); a7 += __shfl_xor(a7, 16, 64); a7 += __shfl_xor(a7, 32, 64);

    if (r == 0) {
        float inv = 1.0f / fmaxf((float)deg, 1.0f);
        size_t o = (size_t)wid * 32 + c * 8;
        float4 r0 = *(const float4*)&y2r[o];
        float4 r1 = *(const float4*)&y2r[o + 4];
        float4 v0, v1;
        v0.x = fmaf(a0, inv, r0.x + b2[c * 8 + 0]);
        v0.y = fmaf(a1, inv, r0.y + b2[c * 8 + 1]);
        v0.z = fmaf(a2, inv, r0.z + b2[c * 8 + 2]);
        v0.w = fmaf(a3, inv, r0.w + b2[c * 8 + 3]);
        v1.x = fmaf(a4, inv, r1.x + b2[c * 8 + 4]);
        v1.y = fmaf(a5, inv, r1.y + b2[c * 8 + 5]);
        v1.z = fmaf(a6, inv, r1.z + b2[c * 8 + 6]);
        v1.w = fmaf(a7, inv, r1.w + b2[c * 8 + 7]);
        *(float4*)&outp[o] = v0;
        *(float4*)&outp[o + 4] = v1;
    }
}

// ---- dense (MFMA): h = relu([mean|x]@W1 + b1); y2l=h@W2l; y2r=h@W2r -----

__global__ __launch_bounds__(256)
void dense_mfma(const ushort* __restrict__ Am,     // mean1 [N][64] bf16
                const ushort* __restrict__ Ax,     // xh [N+1][64] bf16
                const ushort* __restrict__ WB1,    // [64 j][128 k] bf16
                const ushort* __restrict__ WB2,    // [64 j2][64 k] bf16
                const float* __restrict__ b1,      // [64]
                ushort* __restrict__ y2l,          // [N+1][32] bf16
                float* __restrict__ y2r,           // [N][32] fp32
                int N) {
    __shared__ ushort hl[4][16 * 72];   // per-wave h tile, stride 72
    int tid  = threadIdx.x;
    int w    = tid >> 6;
    int lane = tid & 63;
    int mrow = lane & 15;
    int kg   = lane >> 4;
    int nbase = blockIdx.x * 64 + w * 16;
    int arow = min(nbase + mrow, N - 1);

    bf16x8 a[4];
    a[0] = *(const bf16x8*)&Am[(size_t)arow * 64 +      kg * 8];
    a[1] = *(const bf16x8*)&Am[(size_t)arow * 64 + 32 + kg * 8];
    a[2] = *(const bf16x8*)&Ax[(size_t)arow * 64 +      kg * 8];
    a[3] = *(const bf16x8*)&Ax[(size_t)arow * 64 + 32 + kg * 8];

    f32x4 acc[4];
    #pragma unroll
    for (int t = 0; t < 4; ++t) acc[t] = (f32x4){0.f, 0.f, 0.f, 0.f};

    #pragma unroll
    for (int s = 0; s < 4; ++s) {
        #pragma unroll
        for (int t = 0; t < 4; ++t) {
            bf16x8 b = *(const bf16x8*)&WB1[(size_t)(t * 16 + mrow) * 128 + s * 32 + kg * 8];
            acc[t] = __builtin_amdgcn_mfma_f32_16x16x32_bf16(a[s], b, acc[t], 0, 0, 0);
        }
    }

    #pragma unroll
    for (int t = 0; t < 4; ++t) {
        float bv = b1[t * 16 + mrow];
        #pragma unroll
        for (int r = 0; r < 4; ++r) {
            float hv = fmaxf(acc[t][r] + bv, 0.0f);
            hl[w][(kg * 4 + r) * 72 + t * 16 + mrow] = f2bf(hv);
        }
    }
    // same-wave write->read: DS ops in order, no barrier needed

    bf16x8 a2[2];
    a2[0] = *(const bf16x8*)&hl[w][mrow * 72 +      kg * 8];
    a2[1] = *(const bf16x8*)&hl[w][mrow * 72 + 32 + kg * 8];

    f32x4 acc2[4];
    #pragma unroll
    for (int t = 0; t < 4; ++t) acc2[t] = (f32x4){0.f, 0.f, 0.f, 0.f};

    #pragma unroll
    for (int s = 0; s < 2; ++s) {
        #pragma unroll
        for (int t = 0; t < 4; ++t) {
            bf16x8 b = *(const bf16x8*)&WB2[(size_t)(t * 16 + mrow) * 64 + s * 32 + kg * 8];
            acc2[t] = __builtin_amdgcn_mfma_f32_16x16x32_bf16(a2[s], b, acc2[t], 0, 0, 0);
        }
    }

    #pragma unroll
    for (int t = 0; t < 2; ++t) {
        #pragma unroll
        for (int r = 0; r < 4; ++r) {
            int grow = nbase + kg * 4 + r;
            if (grow < N)
                y2l[(size_t)grow * 32 + t * 16 + mrow] = f2bf(acc2[t][r]);
        }
    }
    #pragma unroll
    for (int t = 2; t < 4; ++t) {
        #pragma unroll
        for (int r = 0; r < 4; ++r) {
            int grow = nbase + kg * 4 + r;
            if (grow < N)
                y2r[(size_t)grow * 32 + (t - 2) * 16 + mrow] = acc2[t][r];
        }
    }
}

// ---- launch -------------------------------------------------------------

extern "C" void kernel_launch(void* const* d_in, const int* in_sizes, int n_in,
                              void* d_out, int out_size, void* d_ws, size_t ws_size,
                              hipStream_t stream) {
    const float* x   = (const float*)d_in[0];
    const int*   ei  = (const int*)d_in[1];
    const float* W1l = (const float*)d_in[2];
    const float* W1r = (const float*)d_in[3];
    const float* b1  = (const float*)d_in[4];
    const float* W2l = (const float*)d_in[5];
    const float* W2r = (const float*)d_in[6];
    const float* b2  = (const float*)d_in[7];
    float* out = (float*)d_out;

    int N = in_sizes[0] / D1;
    int E = in_sizes[1] / 2;
    const int* src = ei;
    const int* dst = ei + E;

    char* ws = (char*)d_ws;
    auto alignup = [](size_t v) { return (v + 255) & ~(size_t)255; };
    size_t off = 0;
    int*    tail  = (int*)(ws + off);    off += alignup(NQ * 4);
    int2*   queue = (int2*)(ws + off);   off += alignup((size_t)NQ * QCAP * 8);
    int*    nbr   = (int*)(ws + off);    off += alignup((size_t)NQ * LCAP * 4);
    int2*   info  = (int2*)(ws + off);   off += alignup((size_t)N * 8);
    ushort* xh    = (ushort*)(ws + off); off += alignup((size_t)(N + 1) * D1 * 2);
    ushort* y2l   = (ushort*)(ws + off); off += alignup((size_t)(N + 1) * 32 * 2);
    float*  y2r   = (float*)(ws + off);  off += alignup((size_t)N * 32 * 4);
    ushort* WB1   = (ushort*)(ws + off); off += alignup(64 * 128 * 2);
    ushort* WB2   = (ushort*)(ws + off); off += alignup(64 * 64 * 2);
    // layer-1 mean lives in d_out: written by gather1, read by dense_mfma,
    // then d_out is fully overwritten by gather_out with the final output.
    ushort* mean1 = (ushort*)d_out;      // N*64*2B = 12.8MB == out_size bytes

    int gb = (N + 3) / 4;         // gathers: wave per node, 4 waves/block
    int db = (N + 63) / 64;
    int n4 = N * D1 / 4;
    int cb = (n4 + 255) / 256;
    int ab = (E + BE - 1) / BE;

    hipMemsetAsync(tail, 0, NQ * 4, stream);
    build_and_cvt<<<ab + cb, 256, 0, stream>>>(src, dst, tail, queue, E,
                                               x, xh, y2l,
                                               W1l, W1r, W2l, W2r, WB1, WB2,
                                               n4, N, ab);
    csr_build_local<<<NQ, 256, 0, stream>>>(queue, tail, info, nbr, N);

    gather_mean8<<<gb, 256, 0, stream>>>(xh, info, nbr, mean1, N);
    dense_mfma<<<db, 256, 0, stream>>>(mean1, xh, WB1, WB2, b1, y2l, y2r, N);
    gather_out<<<gb, 256, 0, stream>>>(y2l, y2r, b2, info, nbr, out, N);
}